// Round 3
// baseline (1170.066 us; speedup 1.0000x reference)
//
#include <hip/hip_runtime.h>

// Round 3: 16 batch rows/block (grid 8192), 512 thr (8 waves), 2 blocks/CU
// via __launch_bounds__(512,4) and <=128 regs/thread. Wave wn owns 16 rows x
// hidden [16wn,16wn+16) x 4 gates: acc[4] f32x4 = 16 regs. Whh^T bf16 in regs
// (bfr 64). h double-buffered in LDS (1 barrier/step encoder). Gate algebra in
// packed f32x2 (v_pk_fma_f32), 5 exp2 + 2 rcp per element.

#define OBS_LEN 8
#define PRED_LEN 12
#define BATCH 131072
#define HID 128
#define NZ 512
#define KWT 128
#define KP 136         // LDS h row stride (272 B = 17 quads, balanced banks)
#define ROWS 16

typedef float f32x4 __attribute__((ext_vector_type(4)));
typedef float f32x2 __attribute__((ext_vector_type(2)));
typedef unsigned short u16x8 __attribute__((ext_vector_type(8)));
typedef unsigned short u16x4 __attribute__((ext_vector_type(4)));
typedef __bf16 bf16x8 __attribute__((ext_vector_type(8)));

#define K2F 1.4426950408889634f   // log2(e)

static __device__ __forceinline__ unsigned short f2bf(float f) {
  unsigned int u = __float_as_uint(f);
  u += 0x7FFFu + ((u >> 16) & 1u);
  return (unsigned short)(u >> 16);
}
static __device__ __forceinline__ float bf2f(unsigned short h) {
  return __uint_as_float(((unsigned int)h) << 16);
}

// ---------------- prep: Whh^T bf16 + folded input-embedding scalars ----------
__global__ void prep_weights(const float* __restrict__ We,   const float* __restrict__ be,
                             const float* __restrict__ Wih_e,const float* __restrict__ Whh_e,
                             const float* __restrict__ b_e,
                             const float* __restrict__ Wd,   const float* __restrict__ bd,
                             const float* __restrict__ Wih_d,const float* __restrict__ Whh_d,
                             const float* __restrict__ b_d,
                             unsigned short* __restrict__ wt_enc,
                             unsigned short* __restrict__ wt_dec,
                             float* __restrict__ aux_enc, float* __restrict__ aux_dec) {
  int n = blockIdx.x & (NZ - 1);
  bool dec = blockIdx.x >= NZ;
  const float* Whh = dec ? Whh_d : Whh_e;
  const float* Wih = dec ? Wih_d : Wih_e;
  const float* Wem = dec ? Wd : We;
  const float* bem = dec ? bd : be;
  const float* bl  = dec ? b_d : b_e;
  unsigned short* wt = dec ? wt_dec : wt_enc;
  float* aux = dec ? aux_dec : aux_enc;
  int t = threadIdx.x;
  for (int k = t; k < KWT; k += 64) wt[n * KWT + k] = f2bf(Whh[k * NZ + n]);
  if (t < 3) {
    float s = (t == 2) ? bl[n] : 0.f;
    const float* ve = (t == 0) ? Wem : (t == 1) ? (Wem + HID) : bem;
    for (int e = 0; e < HID; ++e) s += ve[e] * Wih[e * NZ + n];
    aux[t * NZ + n] = s;
  }
}

// ---------------- main fused kernel ----------------
// MFMA 16x16x32 bf16 layouts (HW-verified r1/r2):
//  A: row = lane&15, k = 32kc + (lane>>4)*8 + j
//  C/D: col = lane&15, row = (lane>>4)*4 + reg

#define LOADW(WT, AUX)                                                         \
  {                                                                            \
    _Pragma("unroll")                                                          \
    for (int kc = 0; kc < 4; ++kc) {                                           \
      _Pragma("unroll")                                                        \
      for (int g = 0; g < 4; ++g)                                              \
        bfr[kc][g] = *(const u16x8*)&(WT)[(g * 128 + wn * 16 + l15) * KWT +    \
                                          kc * 32 + l4 * 8];                   \
    }                                                                          \
    _Pragma("unroll")                                                          \
    for (int g = 0; g < 4; ++g) {                                              \
      int n_ = g * 128 + wn * 16 + l15;                                        \
      wx[g] = (AUX)[n_]; wy[g] = (AUX)[NZ + n_]; bb[g] = (AUX)[2 * NZ + n_];   \
    }                                                                          \
  }

#define STEP_MM(CBUF)                                                          \
  {                                                                            \
    _Pragma("unroll")                                                          \
    for (int g = 0; g < 4; ++g)                                                \
      acc[g] = (f32x4){bb[g], bb[g], bb[g], bb[g]};                            \
    _Pragma("unroll")                                                          \
    for (int kc = 0; kc < 4; ++kc) {                                           \
      u16x8 afr = *(const u16x8*)&Als[CBUF][l15 * KP + kc * 32 + l4 * 8];      \
      _Pragma("unroll")                                                        \
      for (int g = 0; g < 4; ++g)                                              \
        acc[g] = __builtin_amdgcn_mfma_f32_16x16x32_bf16(                      \
            __builtin_bit_cast(bf16x8, afr),                                   \
            __builtin_bit_cast(bf16x8, bfr[kc][g]), acc[g], 0, 0, 0);          \
    }                                                                          \
  }

#define EXP2V(d, s)                                                            \
  d[0] = __builtin_amdgcn_exp2f(s[0]); d[1] = __builtin_amdgcn_exp2f(s[1]);
#define RCPV(d, s)                                                             \
  d[0] = __builtin_amdgcn_rcpf(s[0]); d[1] = __builtin_amdgcn_rcpf(s[1]);

// packed-f32 gate phase: input fold + shared-denominator gates + h write
#define GATE_PHASE(PBUF, NBUF)                                                 \
  {                                                                            \
    _Pragma("unroll")                                                          \
    for (int hh = 0; hh < 2; ++hh) {                                           \
      const int rb = l4 * 4 + 2 * hh;                                          \
      f32x2 p0 = *(const f32x2*)&(PBUF)[rb * 2];                               \
      f32x2 p1 = *(const f32x2*)&(PBUF)[rb * 2 + 2];                           \
      f32x2 px2 = (f32x2){p0[0], p1[0]};                                       \
      f32x2 py2 = (f32x2){p0[1], p1[1]};                                       \
      f32x2 z0 = (f32x2){acc[0][2 * hh], acc[0][2 * hh + 1]};                  \
      f32x2 z1 = (f32x2){acc[1][2 * hh], acc[1][2 * hh + 1]};                  \
      f32x2 z2 = (f32x2){acc[2][2 * hh], acc[2][2 * hh + 1]};                  \
      f32x2 z3 = (f32x2){acc[3][2 * hh], acc[3][2 * hh + 1]};                  \
      z0 += px2 * wx[0]; z0 += py2 * wy[0];                                    \
      z1 += px2 * wx[1]; z1 += py2 * wy[1];                                    \
      z2 += px2 * wx[2]; z2 += py2 * wy[2];                                    \
      z3 += px2 * wx[3]; z3 += py2 * wy[3];                                    \
      f32x2 tB = z0 * (-K2F), tA = z1 * (-K2F);                                \
      f32x2 tG = z2 * (-2.f * K2F), tO = z3 * (-K2F);                          \
      f32x2 eA, eB, eG, eO;                                                    \
      EXP2V(eA, tA) EXP2V(eB, tB) EXP2V(eG, tG) EXP2V(eO, tO)                  \
      f32x2 a1 = 1.f + eA, b1 = 1.f + eB, g1 = 1.f + eG;                       \
      f32x2 bg = b1 * g1;                                                      \
      f32x2 den = a1 * bg;                                                     \
      f32x2 rd; RCPV(rd, den)                                                  \
      f32x2 num = crr[hh] * bg + (1.f - eG) * a1;                              \
      f32x2 c2 = num * rd;                                                     \
      crr[hh] = c2;                                                            \
      f32x2 tC = c2 * (-2.f * K2F);                                            \
      f32x2 eC; EXP2V(eC, tC)                                                  \
      f32x2 hn = 1.f - eC;                                                     \
      f32x2 hd = (1.f + eO) * (1.f + eC);                                      \
      f32x2 rh; RCPV(rh, hd)                                                   \
      f32x2 h2 = hn * rh;                                                      \
      Als[NBUF][rb * KP + wn * 16 + l15] = f2bf(h2[0]);                        \
      Als[NBUF][(rb + 1) * KP + wn * 16 + l15] = f2bf(h2[1]);                  \
    }                                                                          \
  }

#define STAGE_OBS(T, PBUF)                                                     \
  if (tid < ROWS) {                                                            \
    float2 p = ((const float2*)obs)[(size_t)(T)*BATCH + row0 + tid];           \
    (PBUF)[tid * 2] = p.x; (PBUF)[tid * 2 + 1] = p.y;                          \
  }

// pos = h @ Wo + bo. 32 threads/row, 4 k each, shfl-reduce (xor 1..16).
#define POS_PHASE(S, HBUF)                                                     \
  {                                                                            \
    const int r = tid >> 5, q = tid & 31;                                      \
    u16x4 hv = *(const u16x4*)&Als[HBUF][r * KP + q * 4];                      \
    f32x2 sxy = (f32x2){0.f, 0.f};                                             \
    _Pragma("unroll")                                                          \
    for (int j = 0; j < 4; ++j) sxy += bf2f(hv[j]) * WoL[q * 4 + j];           \
    _Pragma("unroll")                                                          \
    for (int mk = 1; mk < 32; mk <<= 1) {                                      \
      sxy[0] += __shfl_xor(sxy[0], mk);                                        \
      sxy[1] += __shfl_xor(sxy[1], mk);                                        \
    }                                                                          \
    if (q == 0) {                                                              \
      float pxv = sxy[0] + bo0, pyv = sxy[1] + bo1;                            \
      float2 o; o.x = pxv; o.y = pyv;                                          \
      ((float2*)out)[(size_t)(S)*BATCH + row0 + r] = o;                        \
      posL[0][r * 2] = pxv; posL[0][r * 2 + 1] = pyv;                          \
    }                                                                          \
  }

__global__ __launch_bounds__(512, 4) void lstm_fused(
    const float* __restrict__ obs,
    const unsigned short* __restrict__ wt_enc,
    const unsigned short* __restrict__ wt_dec,
    const float* __restrict__ aux_enc, const float* __restrict__ aux_dec,
    const float* __restrict__ Wo, const float* __restrict__ bo,
    float* __restrict__ out) {
  __shared__ unsigned short Als[2][ROWS * KP];   // h double buffer, bf16
  __shared__ float posL[2][ROWS * 2];
  __shared__ f32x2 WoL[HID];

  const int tid = threadIdx.x;
  const int lane = tid & 63;
  const int wn = tid >> 6;        // hidden slice [16wn,16wn+16)
  const int l15 = lane & 15;
  const int l4 = lane >> 4;
  const int row0 = blockIdx.x * ROWS;

  for (int i = tid; i < ROWS * KP; i += 512) Als[0][i] = 0;  // h0 = 0
  if (tid < HID) WoL[tid] = (f32x2){Wo[tid * 2], Wo[tid * 2 + 1]};
  const float bo0 = bo[0], bo1 = bo[1];

  u16x8 bfr[4][4];       // Whh^T fragments [kc][gate] — persistent, 64 regs
  float wx[4], wy[4], bb[4];
  LOADW(wt_enc, aux_enc);

  f32x4 acc[4];          // [gate]
  f32x2 crr[2];          // c state pairs, f32 forever
  crr[0] = (f32x2){0.f, 0.f};
  crr[1] = (f32x2){0.f, 0.f};

  STAGE_OBS(0, posL[0]);
  __syncthreads();

  int c = 0;
  // ---- encoder: 1 barrier/step (h double-buffered) ----
  for (int t = 0; t < OBS_LEN; ++t) {
    STEP_MM(c);
    GATE_PHASE(posL[t & 1], c ^ 1);
    if (t + 1 < OBS_LEN) STAGE_OBS(t + 1, posL[(t + 1) & 1]);
    __syncthreads();
    c ^= 1;
  }

  // ---- enc -> dec transition ----
  LOADW(wt_dec, aux_dec);
  crr[0] = (f32x2){0.f, 0.f};
  crr[1] = (f32x2){0.f, 0.f};
  POS_PHASE(0, c);                 // pos0 from h_enc -> posL[0], out
  __syncthreads();

  // ---- decoder: 2 barriers/step ----
  for (int s = 1; s < PRED_LEN; ++s) {
    STEP_MM(c);
    GATE_PHASE(posL[0], c ^ 1);
    __syncthreads();               // h visible for POS
    POS_PHASE(s, c ^ 1);
    __syncthreads();               // posL visible for next GATE
    c ^= 1;
  }
}

extern "C" void kernel_launch(void* const* d_in, const int* in_sizes, int n_in,
                              void* d_out, int out_size, void* d_ws, size_t ws_size,
                              hipStream_t stream) {
  const float* obs   = (const float*)d_in[0];
  const float* We    = (const float*)d_in[1];
  const float* be    = (const float*)d_in[2];
  const float* Wih_e = (const float*)d_in[3];
  const float* Whh_e = (const float*)d_in[4];
  const float* b_e   = (const float*)d_in[5];
  const float* Wd    = (const float*)d_in[6];
  const float* bd    = (const float*)d_in[7];
  const float* Wih_d = (const float*)d_in[8];
  const float* Whh_d = (const float*)d_in[9];
  const float* b_d   = (const float*)d_in[10];
  const float* Wo    = (const float*)d_in[11];
  const float* bo    = (const float*)d_in[12];
  float* out = (float*)d_out;

  unsigned short* wt_enc = (unsigned short*)d_ws;                 // 128 KB
  unsigned short* wt_dec = wt_enc + NZ * KWT;                     // +128 KB
  float* aux_enc = (float*)(wt_dec + NZ * KWT);                   // 6 KB
  float* aux_dec = aux_enc + 3 * NZ;

  hipLaunchKernelGGL(prep_weights, dim3(2 * NZ), dim3(64), 0, stream,
                     We, be, Wih_e, Whh_e, b_e, Wd, bd, Wih_d, Whh_d, b_d,
                     wt_enc, wt_dec, aux_enc, aux_dec);
  hipLaunchKernelGGL(lstm_fused, dim3(BATCH / ROWS), dim3(512), 0, stream,
                     obs, wt_enc, wt_dec, aux_enc, aux_dec, Wo, bo, out);
}

// Round 4
// 652.254 us; speedup vs baseline: 1.7939x; 1.7939x over previous
//
#include <hip/hip_runtime.h>

// Round 4: one 1024-thread block (16 waves) per 64 batch rows, 1 block/CU ->
// 4 waves/SIMD (occ ~50%). Wave owns 32 permuted gate-cols (8 hidden units x
// 4 gates): bfr = 32 regs only. Gate combine via 4x shfl_xor(8) per m-tile.
// Decoder pos-path folded into Whh_d (rank-2 update) -> decoder is a pure
// LSTM, POS phase is fire-and-forget, 1 barrier/step everywhere.
// h in LDS bf16 double-buffered; c in f32 regs; packed-f32 gate math.

#define OBS_LEN 8
#define PRED_LEN 12
#define BATCH 131072
#define HID 128
#define NZ 512
#define KWT 128
#define KP 136          // LDS h row stride elems (272 B = 17*16B)
#define ROWS 64

typedef float f32x4 __attribute__((ext_vector_type(4)));
typedef float f32x2 __attribute__((ext_vector_type(2)));
typedef unsigned short u16x8 __attribute__((ext_vector_type(8)));
typedef __bf16 bf16x8 __attribute__((ext_vector_type(8)));

#define K2F 1.4426950408889634f   // log2(e)

static __device__ __forceinline__ unsigned short cvt1(float f) {
  __bf16 b = (__bf16)f;
  return __builtin_bit_cast(unsigned short, b);
}
static __device__ __forceinline__ float bf2f(unsigned short h) {
  return __uint_as_float(((unsigned int)h) << 16);
}

// ---------------- prep ----------------
// Permuted col c in [0,512): wn=c>>5, nt=(c>>4)&1, cc=c&15;
// gate = nt*2 + (cc>>3); unit = wn*8 + (cc&7); logical n = gate*128+unit.
// wt_enc[c][k] = Whh_e[k][n]
// wt_dec[c][k] = Whh_d[k][n] + Wo[k][0]*wxd[n] + Wo[k][1]*wyd[n]   (pos fold)
// aux_enc[{0,1,2}*512+n] = wxe, wye, bbe ; aux_dec[n] = bbd (incl bo fold)
__global__ void prep_weights(const float* __restrict__ We,   const float* __restrict__ be,
                             const float* __restrict__ Wih_e,const float* __restrict__ Whh_e,
                             const float* __restrict__ b_e,
                             const float* __restrict__ Wd,   const float* __restrict__ bd,
                             const float* __restrict__ Wih_d,const float* __restrict__ Whh_d,
                             const float* __restrict__ b_d,
                             const float* __restrict__ Wo,   const float* __restrict__ bo,
                             unsigned short* __restrict__ wt_enc,
                             unsigned short* __restrict__ wt_dec,
                             float* __restrict__ aux_enc, float* __restrict__ aux_dec) {
  const int c = blockIdx.x & (NZ - 1);
  const bool dec = blockIdx.x >= NZ;
  const int wn = c >> 5, nt = (c >> 4) & 1, cc = c & 15;
  const int gate = nt * 2 + (cc >> 3);
  const int unit = wn * 8 + (cc & 7);
  const int n = gate * HID + unit;

  const float* Whh = dec ? Whh_d : Whh_e;
  const float* Wih = dec ? Wih_d : Wih_e;
  const float* Wem = dec ? Wd : We;
  const float* bem = dec ? bd : be;
  const float* bl  = dec ? b_d : b_e;
  unsigned short* wt = dec ? wt_dec : wt_enc;

  float wx = 0.f, wy = 0.f;
  for (int e = 0; e < HID; ++e) {
    wx += Wem[e] * Wih[e * NZ + n];
    wy += Wem[HID + e] * Wih[e * NZ + n];
  }
  for (int k = threadIdx.x; k < KWT; k += 64) {
    float v = Whh[k * NZ + n];
    if (dec) v += Wo[k * 2] * wx + Wo[k * 2 + 1] * wy;
    wt[c * KWT + k] = cvt1(v);
  }
  if (threadIdx.x == 0) {
    float bb = bl[n];
    for (int e = 0; e < HID; ++e) bb += bem[e] * Wih[e * NZ + n];
    if (!dec) {
      aux_enc[n] = wx; aux_enc[NZ + n] = wy; aux_enc[2 * NZ + n] = bb;
    } else {
      aux_dec[n] = bb + bo[0] * wx + bo[1] * wy;
    }
  }
}

// ---------------- main fused kernel ----------------
// MFMA 16x16x32 bf16 layouts (HW-verified r1-r3):
//  A/B frag: row/col = lane&15, k = 32kc + (lane>>4)*8 + j
//  C/D: col = lane&15, row = (lane>>4)*4 + reg

#define EXP2V(d, s)                                                            \
  d[0] = __builtin_amdgcn_exp2f(s[0]); d[1] = __builtin_amdgcn_exp2f(s[1]);
#define RCPV(d, s)                                                             \
  d[0] = __builtin_amdgcn_rcpf(s[0]); d[1] = __builtin_amdgcn_rcpf(s[1]);

#define LOADW(WT)                                                              \
  {                                                                            \
    _Pragma("unroll")                                                          \
    for (int kc = 0; kc < 4; ++kc) {                                           \
      _Pragma("unroll")                                                        \
      for (int nt = 0; nt < 2; ++nt)                                           \
        bfr[kc][nt] = *(const u16x8*)&(WT)[(wn * 32 + nt * 16 + l15) * KWT +   \
                                           kc * 32 + l4 * 8];                  \
    }                                                                          \
  }

#define STEP_MM(CBUF)                                                          \
  {                                                                            \
    _Pragma("unroll")                                                          \
    for (int m = 0; m < 4; ++m) {                                              \
      _Pragma("unroll")                                                        \
      for (int nt = 0; nt < 2; ++nt)                                           \
        acc[m][nt] = (f32x4){bcol[nt], bcol[nt], bcol[nt], bcol[nt]};          \
    }                                                                          \
    _Pragma("unroll")                                                          \
    for (int kc = 0; kc < 4; ++kc) {                                           \
      u16x8 afr[4];                                                            \
      _Pragma("unroll")                                                        \
      for (int m = 0; m < 4; ++m)                                              \
        afr[m] = *(const u16x8*)&Als[CBUF][(16 * m + l15) * KP +               \
                                           kc * 32 + l4 * 8];                  \
      _Pragma("unroll")                                                        \
      for (int nt = 0; nt < 2; ++nt) {                                         \
        _Pragma("unroll")                                                      \
        for (int m = 0; m < 4; ++m)                                            \
          acc[m][nt] = __builtin_amdgcn_mfma_f32_16x16x32_bf16(                \
              __builtin_bit_cast(bf16x8, afr[m]),                              \
              __builtin_bit_cast(bf16x8, bfr[kc][nt]), acc[m][nt], 0, 0, 0);   \
      }                                                                        \
    }                                                                          \
  }

// FOLD: encoder adds px*wxc + py*wyc per column before the gate exchange.
#define GATE_PHASE(FOLD, PBUF, NBUF)                                           \
  {                                                                            \
    _Pragma("unroll")                                                          \
    for (int m = 0; m < 4; ++m) {                                              \
      f32x2 z0l = (f32x2){acc[m][0][0], acc[m][0][1]};                         \
      f32x2 z0h = (f32x2){acc[m][0][2], acc[m][0][3]};                         \
      f32x2 z1l = (f32x2){acc[m][1][0], acc[m][1][1]};                         \
      f32x2 z1h = (f32x2){acc[m][1][2], acc[m][1][3]};                         \
      if (FOLD) {                                                              \
        const float* pb = &(PBUF)[(16 * m + l4 * 4) * 2];                      \
        f32x4 pA = *(const f32x4*)pb;                                          \
        f32x4 pB = *(const f32x4*)(pb + 4);                                    \
        f32x2 pxa = (f32x2){pA[0], pA[2]}, pya = (f32x2){pA[1], pA[3]};        \
        f32x2 pxb = (f32x2){pB[0], pB[2]}, pyb = (f32x2){pB[1], pB[3]};        \
        z0l += pxa * wxc[0] + pya * wyc[0];                                    \
        z0h += pxb * wxc[0] + pyb * wyc[0];                                    \
        z1l += pxa * wxc[1] + pya * wyc[1];                                    \
        z1h += pxb * wxc[1] + pyb * wyc[1];                                    \
      }                                                                        \
      float t0 = __shfl_xor(hi ? z0l[0] : z0h[0], 8);                          \
      float t1 = __shfl_xor(hi ? z0l[1] : z0h[1], 8);                          \
      float t2 = __shfl_xor(hi ? z1l[0] : z1h[0], 8);                          \
      float t3 = __shfl_xor(hi ? z1l[1] : z1h[1], 8);                          \
      f32x2 zi, zf, zg, zo;                                                    \
      zi[0] = hi ? t0 : z0l[0];      zi[1] = hi ? t1 : z0l[1];                 \
      zf[0] = hi ? z0h[0] : t0;      zf[1] = hi ? z0h[1] : t1;                 \
      zg[0] = hi ? t2 : z1l[0];      zg[1] = hi ? t3 : z1l[1];                 \
      zo[0] = hi ? z1h[0] : t2;      zo[1] = hi ? z1h[1] : t3;                 \
      f32x2 tB = zi * (-K2F), tA = zf * (-K2F);                                \
      f32x2 tG = zg * (-2.f * K2F), tO = zo * (-K2F);                          \
      f32x2 eA, eB, eG, eO;                                                    \
      EXP2V(eA, tA) EXP2V(eB, tB) EXP2V(eG, tG) EXP2V(eO, tO)                  \
      f32x2 a1 = 1.f + eA, b1 = 1.f + eB, g1 = 1.f + eG;                       \
      f32x2 bg = b1 * g1;                                                      \
      f32x2 rd; RCPV(rd, (a1 * bg))                                            \
      f32x2 num = crr[m] * bg + (1.f - eG) * a1;                               \
      f32x2 c2 = num * rd;                                                     \
      crr[m] = c2;                                                             \
      f32x2 tC = c2 * (-2.f * K2F);                                            \
      f32x2 eC; EXP2V(eC, tC)                                                  \
      f32x2 hd = (1.f + eO) * (1.f + eC);                                      \
      f32x2 rh; RCPV(rh, hd)                                                   \
      f32x2 h2 = (1.f - eC) * rh;                                              \
      const int R = 16 * m + l4 * 4 + 2 * hi;                                  \
      Als[NBUF][R * KP + ua] = cvt1(h2[0]);                                    \
      Als[NBUF][(R + 1) * KP + ua] = cvt1(h2[1]);                              \
    }                                                                          \
  }

#define STAGE_OBS(T, PBUF)                                                     \
  if (tid < ROWS) {                                                            \
    float2 p = ((const float2*)obs)[(size_t)(T)*BATCH + row0 + tid];           \
    (PBUF)[tid * 2] = p.x; (PBUF)[tid * 2 + 1] = p.y;                          \
  }

// pos = h @ Wo + bo, fire-and-forget to global. 16 threads/row, 8 units each.
#define POS_PHASE(S, HB)                                                       \
  {                                                                            \
    const int r = tid >> 4, q = tid & 15;                                      \
    u16x8 hv = *(const u16x8*)&Als[HB][r * KP + q * 8];                        \
    f32x2 sxy = (f32x2){0.f, 0.f};                                             \
    _Pragma("unroll")                                                          \
    for (int j = 0; j < 8; ++j) sxy += bf2f(hv[j]) * WoL[q * 8 + j];           \
    _Pragma("unroll")                                                          \
    for (int mk = 1; mk < 16; mk <<= 1) {                                      \
      sxy[0] += __shfl_xor(sxy[0], mk);                                        \
      sxy[1] += __shfl_xor(sxy[1], mk);                                        \
    }                                                                          \
    if (q == 0) {                                                              \
      float2 o; o.x = sxy[0] + bo0; o.y = sxy[1] + bo1;                        \
      ((float2*)out)[(size_t)(S)*BATCH + row0 + r] = o;                        \
    }                                                                          \
  }

__global__ __launch_bounds__(1024, 1) void lstm_fused(
    const float* __restrict__ obs,
    const unsigned short* __restrict__ wt_enc,
    const unsigned short* __restrict__ wt_dec,
    const float* __restrict__ aux_enc, const float* __restrict__ aux_dec,
    const float* __restrict__ Wo, const float* __restrict__ bo,
    float* __restrict__ out) {
  __shared__ unsigned short Als[2][ROWS * KP];   // h double buffer, bf16
  __shared__ float posL[2][ROWS * 2];
  __shared__ f32x2 WoL[HID];

  const int tid = threadIdx.x;
  const int lane = tid & 63;
  const int wn = tid >> 6;          // wave 0..15 -> units [8wn, 8wn+8)
  const int l15 = lane & 15;
  const int l4 = lane >> 4;
  const int hi = l15 >> 3;          // 0: rows r0,r1 ; 1: rows r2,r3
  const int ua = wn * 8 + (l15 & 7);  // this lane's hidden unit
  const int row0 = blockIdx.x * ROWS;

  for (int i = tid; i < ROWS * KP; i += 1024) Als[0][i] = 0;   // h0 = 0
  if (tid < HID) WoL[tid] = (f32x2){Wo[tid * 2], Wo[tid * 2 + 1]};
  const float bo0 = bo[0], bo1 = bo[1];

  u16x8 bfr[4][2];       // B frags [kc][ntile] — 32 regs
  float wxc[2], wyc[2], bcol[2];
  LOADW(wt_enc);
  {
    // per-column aux for this lane's two tiles (encoder fold + bias)
    _Pragma("unroll")
    for (int nt = 0; nt < 2; ++nt) {
      int n_ = (nt * 2 + (l15 >> 3)) * HID + ua;
      wxc[nt] = aux_enc[n_]; wyc[nt] = aux_enc[NZ + n_];
      bcol[nt] = aux_enc[2 * NZ + n_];
    }
  }

  f32x4 acc[4][2];       // [m][ntile]
  f32x2 crr[4];          // c state: unit ua, rows (16m + l4*4 + 2hi) + {0,1}
#pragma unroll
  for (int m = 0; m < 4; ++m) crr[m] = (f32x2){0.f, 0.f};

  STAGE_OBS(0, posL[0]);
  __syncthreads();

  int c = 0;
  // ---- encoder: 1 barrier/step ----
  for (int t = 0; t < OBS_LEN; ++t) {
    STEP_MM(c);
    GATE_PHASE(1, posL[t & 1], c ^ 1);
    if (t + 1 < OBS_LEN) STAGE_OBS(t + 1, posL[(t + 1) & 1]);
    __syncthreads();
    c ^= 1;
  }

  // ---- enc -> dec transition (pos-path folded into wt_dec) ----
  LOADW(wt_dec);
#pragma unroll
  for (int nt = 0; nt < 2; ++nt)
    bcol[nt] = aux_dec[(nt * 2 + (l15 >> 3)) * HID + ua];
#pragma unroll
  for (int m = 0; m < 4; ++m) crr[m] = (f32x2){0.f, 0.f};

  // ---- decoder: 1 barrier/step; POS(s-1) overlaps step s's MFMA ----
  for (int s = 1; s < PRED_LEN; ++s) {
    STEP_MM(c);
    POS_PHASE(s - 1, c);
    GATE_PHASE(0, posL[0], c ^ 1);
    __syncthreads();
    c ^= 1;
  }
  POS_PHASE(PRED_LEN - 1, c);
}

extern "C" void kernel_launch(void* const* d_in, const int* in_sizes, int n_in,
                              void* d_out, int out_size, void* d_ws, size_t ws_size,
                              hipStream_t stream) {
  const float* obs   = (const float*)d_in[0];
  const float* We    = (const float*)d_in[1];
  const float* be    = (const float*)d_in[2];
  const float* Wih_e = (const float*)d_in[3];
  const float* Whh_e = (const float*)d_in[4];
  const float* b_e   = (const float*)d_in[5];
  const float* Wd    = (const float*)d_in[6];
  const float* bd    = (const float*)d_in[7];
  const float* Wih_d = (const float*)d_in[8];
  const float* Whh_d = (const float*)d_in[9];
  const float* b_d   = (const float*)d_in[10];
  const float* Wo    = (const float*)d_in[11];
  const float* bo    = (const float*)d_in[12];
  float* out = (float*)d_out;

  unsigned short* wt_enc = (unsigned short*)d_ws;                 // 128 KB
  unsigned short* wt_dec = wt_enc + NZ * KWT;                     // +128 KB
  float* aux_enc = (float*)(wt_dec + NZ * KWT);                   // 6 KB
  float* aux_dec = aux_enc + 3 * NZ;                              // 2 KB

  hipLaunchKernelGGL(prep_weights, dim3(2 * NZ), dim3(64), 0, stream,
                     We, be, Wih_e, Whh_e, b_e, Wd, bd, Wih_d, Whh_d, b_d,
                     Wo, bo, wt_enc, wt_dec, aux_enc, aux_dec);
  hipLaunchKernelGGL(lstm_fused, dim3(BATCH / ROWS), dim3(1024), 0, stream,
                     obs, wt_enc, wt_dec, aux_enc, aux_dec, Wo, bo, out);
}